// Round 9
// baseline (73.422 us; speedup 1.0000x reference)
//
#include <hip/hip_runtime.h>

#define NV     6890
#define NCOL   192                 // 64*3 output columns per row
#define NC4    48                  // NCOL/4 float4s per Xt row
#define NELEM  47472100            // NV*NV
#define C4TOT  11868025            // NELEM/4 flat float4 chunks of L
#define NWORDS 185438              // ceil(C4TOT/64) bitmap words
#define SCANB  2048                // scan blocks (8192 waves)
#define SCANW  8192                // scan waves
#define FULLIT 22                  // 8192*22 slots fully in range
#define TRANB  5168                // ceil(NV*NCOL/256) transpose blocks
#define MAIN4  1722                // per-row aligned f4 count (fallback path)
#define SCALE  (1.0f / (64.0f * 6890.0f))

// ---------------------------------------------------------------------------
// Kernel 1 (fused): blocks [0,SCANB) = copy-pattern flat scan of L -> bitmap;
// blocks [SCANB, SCANB+TRANB) = transpose x -> Xt. Independent work, one
// launch. Scan: wave w, slot s = w + it*8192; lane l tests chunk s*64+l;
// one ballot + one 8B store per KB read — nothing else in the vmem stream.
// ---------------------------------------------------------------------------
__global__ __launch_bounds__(256) void scan_transpose_kernel(
    const float* __restrict__ L, const float* __restrict__ x,
    float* __restrict__ Xt, unsigned long long* __restrict__ bm) {
  if (blockIdx.x < SCANB) {
    const int lane = threadIdx.x & 63;
    const int w    = blockIdx.x * 4 + (threadIdx.x >> 6);
    const float4* __restrict__ Lf4 = (const float4*)L;

    #pragma unroll 8
    for (int it = 0; it < FULLIT; ++it) {
      const int s = w + it * SCANW;                 // s < 180224: no guards
      const float4 f = Lf4[(size_t)s * 64 + lane];
      const unsigned u = __float_as_uint(f.x) | __float_as_uint(f.y) |
                         __float_as_uint(f.z) | __float_as_uint(f.w);
      const unsigned long long m = __ballot(u != 0u);
      if (lane == 0) bm[s] = m;
    }
    {                                               // guarded tail slot
      const int s = w + FULLIT * SCANW;
      if (s < NWORDS) {
        const int c = s * 64 + lane;
        float4 f = make_float4(0.f, 0.f, 0.f, 0.f);
        if (c < C4TOT) f = Lf4[c];
        const unsigned u = __float_as_uint(f.x) | __float_as_uint(f.y) |
                           __float_as_uint(f.z) | __float_as_uint(f.w);
        const unsigned long long m = __ballot(u != 0u);
        if (lane == 0) bm[s] = m;
      }
    }
  } else {
    const int t = (blockIdx.x - SCANB) * 256 + threadIdx.x;
    if (t < NV * NCOL) {
      const int n = t % NCOL;
      const int w = t / NCOL;
      Xt[t] = x[(size_t)(n / 3) * (NV * 3) + (size_t)w * 3 + (n % 3)];
    }
  }
}

// ---------------------------------------------------------------------------
// Kernel 2: APPLY. One wave per row. Coalesced load of the row's <=28 bitmap
// words; uniform bit-walk; each flagged 16B chunk re-read from L (uniform
// address -> broadcast, L3-resident); per in-row nonzero component: lanes
// 0..47 gather the column's 768B Xt row + 4 FMAs. Ascending-chunk order ->
// deterministic, same order as previous rounds.
// ---------------------------------------------------------------------------
__global__ __launch_bounds__(256) void apply_kernel(
    const float* __restrict__ L, const float* __restrict__ Xt,
    const unsigned long long* __restrict__ bm, float* __restrict__ partials) {
  const int lane = threadIdx.x & 63;
  const int wv   = threadIdx.x >> 6;
  const int v    = blockIdx.x * 4 + wv;
  if (v >= NV) return;

  const int rbase  = v * NV;
  const int rend   = rbase + NV;
  const int cfirst = rbase >> 2;
  const int clast  = (rend - 1) >> 2;
  const int w0     = cfirst >> 6;
  const int nw     = (clast >> 6) - w0 + 1;        // <= 28

  const unsigned long long myw =
      (lane < nw) ? bm[w0 + lane] : 0ull;          // one coalesced load

  const float4* __restrict__ Lf4 = (const float4*)L;
  const float4* __restrict__ Xt4 = (const float4*)Xt;
  float4 acc = make_float4(0.f, 0.f, 0.f, 0.f);

  auto gatherc = [&](float val, int col) {
    if (lane < NC4) {
      const float4 g = Xt4[(size_t)col * NC4 + lane];
      acc.x = fmaf(val, g.x, acc.x);
      acc.y = fmaf(val, g.y, acc.y);
      acc.z = fmaf(val, g.z, acc.z);
      acc.w = fmaf(val, g.w, acc.w);
    }
  };

  for (int j = 0; j < nw; ++j) {                   // uniform loop
    unsigned long long word = __shfl(myw, j);
    const int lo = (j == 0) ? (cfirst & 63) : 0;
    const int hi = (j == nw - 1) ? (clast & 63) : 63;
    word &= (~0ull >> (63 - hi)) & (~0ull << lo);
    while (word) {                                 // uniform bit-walk
      const int s = (int)__builtin_ctzll(word);
      word &= word - 1;
      const int c = (w0 + j) * 64 + s;
      const float4 f = Lf4[c];                     // uniform addr: broadcast
      const int e0 = c * 4;
      if (e0 >= rbase && e0 < rend && __float_as_uint(f.x)) gatherc(f.x, e0 - rbase);
      const int e1 = e0 + 1;
      if (e1 >= rbase && e1 < rend && __float_as_uint(f.y)) gatherc(f.y, e1 - rbase);
      const int e2 = e0 + 2;
      if (e2 >= rbase && e2 < rend && __float_as_uint(f.z)) gatherc(f.z, e2 - rbase);
      const int e3 = e0 + 3;
      if (e3 >= rbase && e3 < rend && __float_as_uint(f.w)) gatherc(f.w, e3 - rbase);
    }
  }

  float sq = fmaf(acc.x, acc.x,
             fmaf(acc.y, acc.y,
             fmaf(acc.z, acc.z, acc.w * acc.w)));
  #pragma unroll
  for (int o = 32; o > 0; o >>= 1) sq += __shfl_down(sq, o);
  if (lane == 0) partials[v] = sq;
}

// ---------------------------------------------------------------------------
// Fallback fused kernel (tiny ws): bit-walk, gathers from x directly.
// ---------------------------------------------------------------------------
template <bool USE_PARTIALS>
__global__ __launch_bounds__(256) void lap_fused_kernel(
    const float* __restrict__ L, const float* __restrict__ x,
    float* __restrict__ partials, float* __restrict__ out_atomic) {
  const int lane = threadIdx.x & 63;
  const int wv   = threadIdx.x >> 6;
  const int v    = blockIdx.x * 4 + wv;
  if (v >= NV) return;

  const float* __restrict__ row = L + (size_t)v * NV;
  const int head     = (v & 1) ? 2 : 0;
  const int extraPos = head ? 0 : (NV - 2);
  const float4* __restrict__ m4 = (const float4*)(row + head);

  const int n0 = lane, n1 = lane + 64, n2 = lane + 128;
  const int o0 = (n0 / 3) * (NV * 3) + (n0 % 3);
  const int o1 = (n1 / 3) * (NV * 3) + (n1 % 3);
  const int o2 = (n2 / 3) * (NV * 3) + (n2 % 3);

  float a0 = 0.f, a1 = 0.f, a2 = 0.f;
  auto walk = [&](unsigned long long m, float src, int col0, int stride) {
    while (m) {
      const int s = (int)__builtin_ctzll(m);
      m &= m - 1;
      const float val =
          __int_as_float(__builtin_amdgcn_readlane(__float_as_int(src), s));
      const int cb = (col0 + s * stride) * 3;
      a0 = fmaf(val, x[cb + o0], a0);
      a1 = fmaf(val, x[cb + o1], a1);
      a2 = fmaf(val, x[cb + o2], a2);
    }
  };
  {
    const bool act = lane < 2;
    const float val = act ? row[extraPos + lane] : 0.f;
    walk(__ballot(act && val != 0.f), val, extraPos, 1);
  }
  for (int it = 0; it < 27; ++it) {
    const int i = it * 64 + lane;
    const bool act = i < MAIN4;
    float4 f = make_float4(0.f, 0.f, 0.f, 0.f);
    if (act) f = m4[i];
    const int cb = head + it * 256;
    walk(__ballot(act && f.x != 0.f), f.x, cb + 0, 4);
    walk(__ballot(act && f.y != 0.f), f.y, cb + 1, 4);
    walk(__ballot(act && f.z != 0.f), f.z, cb + 2, 4);
    walk(__ballot(act && f.w != 0.f), f.w, cb + 3, 4);
  }

  float sq = fmaf(a0, a0, fmaf(a1, a1, a2 * a2));
  #pragma unroll
  for (int o = 32; o > 0; o >>= 1) sq += __shfl_down(sq, o);
  if (lane == 0) {
    if (USE_PARTIALS) partials[v] = sq;
    else              atomicAdd(out_atomic, sq * SCALE);
  }
}

// ---------------------------------------------------------------------------
// Kernel 3: deterministic fixed-order reduction of the 6890 row partials.
// ---------------------------------------------------------------------------
__global__ __launch_bounds__(256) void reduce_kernel(
    const float* __restrict__ p, float* __restrict__ out) {
  int tid = threadIdx.x;
  float a = 0.0f;
  for (int i = tid; i < NV; i += 256) a += p[i];
  #pragma unroll
  for (int o = 32; o > 0; o >>= 1) a += __shfl_down(a, o);
  __shared__ float s_w[4];
  if ((tid & 63) == 0) s_w[tid >> 6] = a;
  __syncthreads();
  if (tid == 0) out[0] = (s_w[0] + s_w[1] + s_w[2] + s_w[3]) * SCALE;
}

__global__ void zero_out_kernel(float* p) {
  if (threadIdx.x == 0 && blockIdx.x == 0) p[0] = 0.0f;
}

// ---------------------------------------------------------------------------
extern "C" void kernel_launch(void* const* d_in, const int* in_sizes, int n_in,
                              void* d_out, int out_size, void* d_ws, size_t ws_size,
                              hipStream_t stream) {
  const float* x = (const float*)d_in[0];   // [64, 6890, 3] f32
  const float* L = (const float*)d_in[1];   // [6890, 6890] f32
  float* out = (float*)d_out;               // scalar f32

  const size_t xt_bytes   = (size_t)NV * NCOL * sizeof(float);         // ~5.29 MB
  const size_t bm_bytes   = ((size_t)NWORDS * 8 + 255) & ~(size_t)255; // ~1.48 MB
  const size_t part_bytes = (size_t)NV * sizeof(float);                // ~27.5 KB

  if (ws_size >= xt_bytes + bm_bytes + part_bytes) {
    char* p = (char*)d_ws;
    float*              Xt       = (float*)p;               p += xt_bytes;
    unsigned long long* bm       = (unsigned long long*)p;  p += bm_bytes;
    float*              partials = (float*)p;

    scan_transpose_kernel<<<SCANB + TRANB, 256, 0, stream>>>(L, x, Xt, bm);
    apply_kernel<<<(NV + 3) / 4, 256, 0, stream>>>(L, Xt, bm, partials);
    reduce_kernel<<<1, 256, 0, stream>>>(partials, out);
  } else if (ws_size >= part_bytes) {
    float* partials = (float*)d_ws;
    lap_fused_kernel<true><<<(NV + 3) / 4, 256, 0, stream>>>(L, x, partials, nullptr);
    reduce_kernel<<<1, 256, 0, stream>>>(partials, out);
  } else {
    zero_out_kernel<<<1, 64, 0, stream>>>(out);
    lap_fused_kernel<false><<<(NV + 3) / 4, 256, 0, stream>>>(L, x, nullptr, out);
  }
}